// Round 4
// baseline (1957.090 us; speedup 1.0000x reference)
//
#include <hip/hip_runtime.h>

#define TT 16
#define DD 512
#define HIDN 512
#define OUTN 7
#define NTOT 1024          // G cols: gc pre-act 0..511, d1-top pre-act 512..1023
#define R2 8               // rows per block in recurrent kernel

typedef __attribute__((ext_vector_type(8))) _Float16 half8;
typedef __attribute__((ext_vector_type(4))) float f32x4;

// async global->LDS, 16B/lane; LDS dest = wave-uniform base (+ lane*16 by HW)
#define GLD_LDS(g, l) __builtin_amdgcn_global_load_lds(                     \
    (const __attribute__((address_space(1))) void*)(g),                     \
    (__attribute__((address_space(3))) void*)(l), 16, 0, 0)

// ---- weight pre-pack: fp32 -> (hi,lo) f16 in MFMA B-fragment order ----------
// cell = (ct, ks, lane); elem j = W[k = ks*32 + (lane>>4)*8 + j][col],
// col = ct'*16 + (lane&15); ct<32 -> Wgc tile ct, ct>=32 -> Wd1-top tile ct-32.
__global__ void pack_w(const float* __restrict__ Wgc, const float* __restrict__ Wd1,
                       _Float16* __restrict__ Whi, _Float16* __restrict__ Wlo)
{
    const int cell = blockIdx.x * blockDim.x + threadIdx.x;    // 64*16*64 = 65536
    const int lane = cell & 63;
    const int ks   = (cell >> 6) & 15;
    const int ct   = cell >> 10;
    const float* W = (ct < 32) ? Wgc : Wd1;
    const int col  = ((ct < 32) ? ct : ct - 32) * 16 + (lane & 15);
    const int k0   = ks * 32 + ((lane >> 4) << 3);
    half8 vh, vl;
#pragma unroll
    for (int j = 0; j < 8; ++j) {
        const float w = W[(size_t)(k0 + j) * HIDN + col];
        const _Float16 h = (_Float16)w;
        vh[j] = h;
        vl[j] = (_Float16)(w - (float)h);
    }
    *reinterpret_cast<half8*>(Whi + (size_t)cell * 8) = vh;
    *reinterpret_cast<half8*>(Wlo + (size_t)cell * 8) = vl;
}

// ---- x pre-pack: fp32 -> (hi,lo) f16 in MFMA A-fragment order ---------------
// one block per 16-row group (sub); cell (sub, ks, lane):
// elem j = x[row = sub*16 + (lane&15)][k = ks*32 + (lane>>4)*8 + j]
__global__ void pack_x(const float* __restrict__ x,
                       _Float16* __restrict__ Xh, _Float16* __restrict__ Xl)
{
    __shared__ float xs[16 * 516];                  // padded: gather ~conflict-free
    const int tid = threadIdx.x;
    const size_t sub = blockIdx.x;
    const float* src = x + sub * (16 * DD);
#pragma unroll
    for (int u = 0; u < 8; ++u) {                   // coalesced 16x512 f32 load
        const int f = (u << 8) + tid;               // float4 id 0..2047
        const int row = f >> 7, c4 = f & 127;
        const float4 v = *reinterpret_cast<const float4*>(src + ((size_t)f << 2));
        *reinterpret_cast<float4*>(&xs[row * 516 + (c4 << 2)]) = v;
    }
    __syncthreads();
#pragma unroll
    for (int i = 0; i < 4; ++i) {
        const int c = (i << 8) + tid;               // cell 0..1023
        const int ks = c >> 6, lane = c & 63;
        const int row16 = lane & 15, kq = lane >> 4;
        const float* p = &xs[row16 * 516 + ks * 32 + (kq << 3)];
        half8 vh, vl;
#pragma unroll
        for (int j = 0; j < 8; ++j) {
            const float f0 = p[j];
            const _Float16 h = (_Float16)f0;
            vh[j] = h;
            vl[j] = (_Float16)(f0 - (float)h);
        }
        const size_t o = ((sub * 16 + ks) * 64 + lane) * 8;   // coalesced 16B
        *reinterpret_cast<half8*>(Xh + o) = vh;
        *reinterpret_cast<half8*>(Xl + o) = vl;
    }
}

// ---- Phase 1: G = X @ [Wgc | Wd1top]  (fp32 via f16 hi/lo, 3 products) ------
// 128x128 tile, BK=32, 4 waves (2x2), 4x4 16x16x32 frags/wave. A and B both
// pre-packed in fragment order -> all staging via global_load_lds, zero VALU
// conversion in the K-loop. Double-buffered, 1 barrier per K-step.
__global__ __launch_bounds__(256, 2)
void gemm_pre(const _Float16* __restrict__ Xh, const _Float16* __restrict__ Xl,
              const _Float16* __restrict__ Whi, const _Float16* __restrict__ Wlo,
              float* __restrict__ G, int nrt)
{
    __shared__ __align__(16) _Float16 Ah[2][4096];   // [buf][rowgrp(8)][lane(64)][8]
    __shared__ __align__(16) _Float16 Al[2][4096];
    __shared__ __align__(16) _Float16 Bh[2][4096];   // [buf][colgrp(8)][lane(64)][8]
    __shared__ __align__(16) _Float16 Bl[2][4096];

    const int tid  = threadIdx.x;
    const int lane = tid & 63;
    const int wave = tid >> 6;
    const int wr   = wave >> 1;
    const int wc   = wave & 1;

    // XCD-bijective swizzle: the 8 col-blocks of one row-tile land on ONE XCD,
    // so the shared A-panel is fetched into that XCD's L2 once (requires
    // grid % 8 == 0 and nrt % 8 == 0 -- guarded by the launcher).
    const int disp = blockIdx.x;
    const int xcd  = disp & 7;
    const int q    = disp >> 3;
    const int rt   = xcd * (nrt >> 3) + (q >> 3);    // row-tile (128 rows)
    const int ct0  = (q & 7) << 3;                   // first 16-col tile (0..56)

    const int g0 = wave << 1, g1 = g0 + 1;           // this wave's staged groups

    f32x4 acc[4][4];
#pragma unroll
    for (int g = 0; g < 4; ++g)
#pragma unroll
        for (int c = 0; c < 4; ++c) acc[g][c] = (f32x4){0.f, 0.f, 0.f, 0.f};

#define STAGE(kc, BUF)                                                        \
    {                                                                         \
        const size_t sa0 = (((size_t)(rt * 8 + g0) * 16 + (kc)) * 64 + lane) * 8; \
        const size_t sa1 = (((size_t)(rt * 8 + g1) * 16 + (kc)) * 64 + lane) * 8; \
        GLD_LDS(Xh + sa0, &Ah[BUF][g0 << 9]);                                 \
        GLD_LDS(Xl + sa0, &Al[BUF][g0 << 9]);                                 \
        GLD_LDS(Xh + sa1, &Ah[BUF][g1 << 9]);                                 \
        GLD_LDS(Xl + sa1, &Al[BUF][g1 << 9]);                                 \
        const size_t sb0 = (((size_t)(ct0 + g0) * 16 + (kc)) * 64 + lane) * 8;\
        const size_t sb1 = (((size_t)(ct0 + g1) * 16 + (kc)) * 64 + lane) * 8;\
        GLD_LDS(Whi + sb0, &Bh[BUF][g0 << 9]);                                \
        GLD_LDS(Wlo + sb0, &Bl[BUF][g0 << 9]);                                \
        GLD_LDS(Whi + sb1, &Bh[BUF][g1 << 9]);                                \
        GLD_LDS(Wlo + sb1, &Bl[BUF][g1 << 9]);                                \
    }

#define COMPUTE(BUF)                                                          \
    {                                                                         \
        half8 af[4], alf[4];                                                  \
        _Pragma("unroll")                                                     \
        for (int g = 0; g < 4; ++g) {                                         \
            const int o = (((wr << 2) + g) * 64 + lane) * 8;                  \
            af[g]  = *reinterpret_cast<const half8*>(&Ah[BUF][o]);            \
            alf[g] = *reinterpret_cast<const half8*>(&Al[BUF][o]);            \
        }                                                                     \
        _Pragma("unroll")                                                     \
        for (int c = 0; c < 4; ++c) {                                         \
            const int o = (((wc << 2) + c) * 64 + lane) * 8;                  \
            const half8 bf  = *reinterpret_cast<const half8*>(&Bh[BUF][o]);   \
            const half8 blf = *reinterpret_cast<const half8*>(&Bl[BUF][o]);   \
            _Pragma("unroll")                                                 \
            for (int g = 0; g < 4; ++g) {                                     \
                acc[g][c] = __builtin_amdgcn_mfma_f32_16x16x32_f16(af[g],  bf,  acc[g][c], 0, 0, 0); \
                acc[g][c] = __builtin_amdgcn_mfma_f32_16x16x32_f16(alf[g], bf,  acc[g][c], 0, 0, 0); \
                acc[g][c] = __builtin_amdgcn_mfma_f32_16x16x32_f16(af[g],  blf, acc[g][c], 0, 0, 0); \
            }                                                                 \
        }                                                                     \
    }

    STAGE(0, 0);
    __syncthreads();

#pragma unroll 1
    for (int kh = 0; kh < 8; ++kh) {
        STAGE(2 * kh + 1, 1);
        COMPUTE(0);
        __syncthreads();                // drains buf1 staging + ends buf0 reads
        if (2 * kh + 2 < 16) STAGE(2 * kh + 2, 0);
        COMPUTE(1);
        __syncthreads();
    }

    // epilogue: C layout row=(lane>>4)*4+j, col=lane&15 (m89-verified)
    const int r0 = (lane >> 4) << 2;
    const int cl = lane & 15;
    const size_t m0 = (size_t)rt << 7;
#pragma unroll
    for (int g = 0; g < 4; ++g)
#pragma unroll
        for (int c = 0; c < 4; ++c) {
            float* gp = G + (m0 + (size_t)((wr << 6) + (g << 4) + r0)) * NTOT
                          + (ct0 << 4) + (wc << 6) + (c << 4) + cl;
#pragma unroll
            for (int j = 0; j < 4; ++j)
                __builtin_nontemporal_store(acc[g][c][j], gp + (size_t)j * NTOT);
        }
#undef STAGE
#undef COMPUTE
}

// ---- Phase 2: recurrent LIF + sparse spike-driven layers over G -------------
__global__ __launch_bounds__(256, 4)
void snn_recur(const float* __restrict__ G, const float* __restrict__ bgc,
               const float* __restrict__ Wpc, const float* __restrict__ bpc,
               const float* __restrict__ Wd1, const float* __restrict__ bd1p,
               const float* __restrict__ Wd2, const float* __restrict__ bd2,
               float* __restrict__ out, int Btot)
{
    __shared__ unsigned long long bits1[R2][8];
    __shared__ unsigned long long bits2[R2][8];
    __shared__ unsigned long long bits3[R2][8];
    __shared__ unsigned int rowflag[3];

    const int tid  = threadIdx.x;
    const int lane = tid & 63;
    const int wave = tid >> 6;
    const int row0l = blockIdx.x * R2;

    float m1a[R2], m1b[R2], m2a[R2], m2b[R2], m3a[R2], m3b[R2];
#pragma unroll
    for (int r = 0; r < R2; ++r) {
        m1a[r] = 0.f; m1b[r] = 0.f; m2a[r] = 0.f;
        m2b[r] = 0.f; m3a[r] = 0.f; m3b[r] = 0.f;
    }

    const float bg0 = bgc[tid],  bg1 = bgc[tid + 256];
    const float bp0 = bpc[tid],  bp1 = bpc[tid + 256];
    const float bd0 = bd1p[tid], bd1v = bd1p[tid + 256];

    float out_acc = 0.f;
    const int orow = tid / OUTN;
    const int ocol = tid - orow * OUTN;
    const bool owrite = (tid < R2 * OUTN);

    if (tid < 3) rowflag[tid] = 0u;
    __syncthreads();

#pragma unroll 1
    for (int t = 0; t < TT; ++t) {
        const float* Gt = G + ((size_t)t * Btot + row0l) * NTOT;
        float ga[R2], gb[R2], g2[R2], g3[R2];
#pragma unroll
        for (int r = 0; r < R2; ++r) {
            const float* gp = Gt + (size_t)r * NTOT + tid;
            ga[r] = gp[0]; gb[r] = gp[256]; g2[r] = gp[512]; g3[r] = gp[768];
        }

        // ===== LIF layer 1 (gc) -> bits1 + rowflag[0] =========================
#pragma unroll
        for (int r = 0; r < R2; ++r) {
            const float v0 = m1a[r] + ((ga[r] + bg0) - m1a[r]) * 0.5f;
            const bool s0 = (v0 - 1.0f) > 0.0f;
            m1a[r] = s0 ? 0.0f : v0;
            const unsigned long long k0 = __ballot(s0);
            const float v1 = m1b[r] + ((gb[r] + bg1) - m1b[r]) * 0.5f;
            const bool s1 = (v1 - 1.0f) > 0.0f;
            m1b[r] = s1 ? 0.0f : v1;
            const unsigned long long k1 = __ballot(s1);
            if (lane == 0) {
                bits1[r][wave] = k0; bits1[r][4 + wave] = k1;
                if (k0 | k1) atomicOr(&rowflag[0], 1u << r);
            }
        }
        __syncthreads();                                   // barrier A
        if (tid == 0) rowflag[2] = 0u;

        // ===== layer 2 (pc): sparse bits1 -> bits2 + rowflag[1] ===============
        {
            const unsigned int rf = rowflag[0];
#pragma unroll
            for (int r = 0; r < R2; ++r) {
                float p0 = bp0, p1 = bp1;
                if (rf & (1u << r)) {
#pragma unroll 1
                    for (int w = 0; w < 8; ++w) {
                        unsigned long long mm = bits1[r][w];
                        while (mm) {
                            const int b = __builtin_ctzll(mm); mm &= (mm - 1);
                            const float* wp = Wpc + (size_t)((w << 6) + b) * HIDN + tid;
                            p0 += wp[0]; p1 += wp[256];
                        }
                    }
                }
                const float v0 = m2a[r] + (p0 - m2a[r]) * 0.5f;
                const bool s0 = (v0 - 1.0f) > 0.0f;
                m2a[r] = s0 ? 0.0f : v0;
                const unsigned long long k0 = __ballot(s0);
                const float v1 = m2b[r] + (p1 - m2b[r]) * 0.5f;
                const bool s1 = (v1 - 1.0f) > 0.0f;
                m2b[r] = s1 ? 0.0f : v1;
                const unsigned long long k1 = __ballot(s1);
                if (lane == 0) {
                    bits2[r][wave] = k0; bits2[r][4 + wave] = k1;
                    if (k0 | k1) atomicOr(&rowflag[1], 1u << r);
                }
            }
        }
        __syncthreads();                                   // barrier B
        if (tid == 0) rowflag[0] = 0u;

        // ===== layer 3 (dcn): G d1-part + sparse bits2 -> bits3 ===============
        {
            const unsigned int rf = rowflag[1];
#pragma unroll
            for (int r = 0; r < R2; ++r) {
                float p0 = g2[r] + bd0, p1 = g3[r] + bd1v;
                if (rf & (1u << r)) {
#pragma unroll 1
                    for (int w = 0; w < 8; ++w) {
                        unsigned long long mm = bits2[r][w];
                        while (mm) {
                            const int b = __builtin_ctzll(mm); mm &= (mm - 1);
                            const float* wp = Wd1 + (size_t)(DD + (w << 6) + b) * HIDN + tid;
                            p0 += wp[0]; p1 += wp[256];
                        }
                    }
                }
                const float v0 = m3a[r] + (p0 - m3a[r]) * 0.5f;
                const bool s0 = (v0 - 1.0f) > 0.0f;
                m3a[r] = s0 ? 0.0f : v0;
                const unsigned long long k0 = __ballot(s0);
                const float v1 = m3b[r] + (p1 - m3b[r]) * 0.5f;
                const bool s1 = (v1 - 1.0f) > 0.0f;
                m3b[r] = s1 ? 0.0f : v1;
                const unsigned long long k1 = __ballot(s1);
                if (lane == 0) {
                    bits3[r][wave] = k0; bits3[r][4 + wave] = k1;
                    if (k0 | k1) atomicOr(&rowflag[2], 1u << r);
                }
            }
        }
        __syncthreads();                                   // barrier C
        if (tid == 0) rowflag[1] = 0u;

        // ===== output accumulation over s3 spikes =============================
        {
            const unsigned int rf = rowflag[2];
            if (owrite && (rf & (1u << orow))) {
#pragma unroll 1
                for (int w = 0; w < 8; ++w) {
                    unsigned long long mm = bits3[orow][w];
                    while (mm) {
                        const int b = __builtin_ctzll(mm); mm &= (mm - 1);
                        out_acc += Wd2[(size_t)((w << 6) + b) * OUTN + ocol];
                    }
                }
            }
        }
        // barrier A(t+1) orders these reads vs next overwrites of bits3/flags
    }

    if (owrite)
        out[(size_t)(row0l + orow) * OUTN + ocol] = out_acc * 0.0625f + bd2[ocol];
}

// ---- Fallback: round-0 fused kernel (harness-verified, needs no workspace) --
__global__ __launch_bounds__(256, 2)
void snn_fused_fb(const float* __restrict__ x,
                  const float* __restrict__ Wgc, const float* __restrict__ bgc,
                  const float* __restrict__ Wpc, const float* __restrict__ bpc,
                  const float* __restrict__ Wd1, const float* __restrict__ bd1p,
                  const float* __restrict__ Wd2, const float* __restrict__ bd2,
                  float* __restrict__ out, int B)
{
    __shared__ float xs[16 * DD];
    __shared__ unsigned long long bits1[16][8];
    __shared__ unsigned long long bits2[16][8];
    __shared__ unsigned long long bits3[16][8];
    __shared__ unsigned int rowflag[3];

    const int tid  = threadIdx.x;
    const int lane = tid & 63;
    const int wave = tid >> 6;
    const size_t row0 = (size_t)blockIdx.x * 16;

    float m1a[16], m1b[16], m2a[16], m2b[16], m3a[16], m3b[16];
#pragma unroll
    for (int r = 0; r < 16; ++r) {
        m1a[r] = 0.f; m1b[r] = 0.f; m2a[r] = 0.f;
        m2b[r] = 0.f; m3a[r] = 0.f; m3b[r] = 0.f;
    }

    const float bg0 = bgc[tid],  bg1 = bgc[tid + 256];
    const float bp0 = bpc[tid],  bp1 = bpc[tid + 256];
    const float bd0 = bd1p[tid], bd1 = bd1p[tid + 256];

    float out_acc = 0.f;
    const int orow = tid / OUTN;
    const int ocol = tid - orow * OUTN;
    const bool owrite = (tid < 16 * OUTN);

    if (tid < 3) rowflag[tid] = 0;
    {
        const float* src = x + row0 * DD;
#pragma unroll
        for (int u = 0; u < 8; ++u)
            GLD_LDS(src + ((u * 256 + tid) << 2), xs + ((u * 256 + wave * 64) << 2));
    }
    __syncthreads();

    for (int t = 0; t < TT; ++t) {
        float a0[16], a1[16], a2[16], a3[16];
#pragma unroll
        for (int r = 0; r < 16; ++r) { a0[r] = 0.f; a1[r] = 0.f; a2[r] = 0.f; a3[r] = 0.f; }

        const float* gp = Wgc + tid;
        const float* dp = Wd1 + tid;

        float wA0[4], wA1[4], wA2[4], wA3[4];
        float wB0[4], wB1[4], wB2[4], wB3[4];
#pragma unroll
        for (int u = 0; u < 4; ++u) {
            const size_t o = (size_t)u * HIDN;
            wA0[u] = gp[o]; wA1[u] = gp[o + 256];
            wA2[u] = dp[o]; wA3[u] = dp[o + 256];
        }
#pragma unroll 1
        for (int kk = 0; kk < DD; kk += 8) {
#pragma unroll
            for (int u = 0; u < 4; ++u) {
                const size_t o = (size_t)(kk + 4 + u) * HIDN;
                wB0[u] = gp[o]; wB1[u] = gp[o + 256];
                wB2[u] = dp[o]; wB3[u] = dp[o + 256];
            }
#pragma unroll
            for (int r = 0; r < 16; ++r) {
                const float4 xv = *reinterpret_cast<const float4*>(&xs[r * DD + kk]);
                a0[r] = fmaf(xv.x, wA0[0], a0[r]); a0[r] = fmaf(xv.y, wA0[1], a0[r]);
                a0[r] = fmaf(xv.z, wA0[2], a0[r]); a0[r] = fmaf(xv.w, wA0[3], a0[r]);
                a1[r] = fmaf(xv.x, wA1[0], a1[r]); a1[r] = fmaf(xv.y, wA1[1], a1[r]);
                a1[r] = fmaf(xv.z, wA1[2], a1[r]); a1[r] = fmaf(xv.w, wA1[3], a1[r]);
                a2[r] = fmaf(xv.x, wA2[0], a2[r]); a2[r] = fmaf(xv.y, wA2[1], a2[r]);
                a2[r] = fmaf(xv.z, wA2[2], a2[r]); a2[r] = fmaf(xv.w, wA2[3], a2[r]);
                a3[r] = fmaf(xv.x, wA3[0], a3[r]); a3[r] = fmaf(xv.y, wA3[1], a3[r]);
                a3[r] = fmaf(xv.z, wA3[2], a3[r]); a3[r] = fmaf(xv.w, wA3[3], a3[r]);
            }
            const int k2 = (kk + 8) & (DD - 1);
#pragma unroll
            for (int u = 0; u < 4; ++u) {
                const size_t o = (size_t)(k2 + u) * HIDN;
                wA0[u] = gp[o]; wA1[u] = gp[o + 256];
                wA2[u] = dp[o]; wA3[u] = dp[o + 256];
            }
#pragma unroll
            for (int r = 0; r < 16; ++r) {
                const float4 xv = *reinterpret_cast<const float4*>(&xs[r * DD + kk + 4]);
                a0[r] = fmaf(xv.x, wB0[0], a0[r]); a0[r] = fmaf(xv.y, wB0[1], a0[r]);
                a0[r] = fmaf(xv.z, wB0[2], a0[r]); a0[r] = fmaf(xv.w, wB0[3], a0[r]);
                a1[r] = fmaf(xv.x, wB1[0], a1[r]); a1[r] = fmaf(xv.y, wB1[1], a1[r]);
                a1[r] = fmaf(xv.z, wB1[2], a1[r]); a1[r] = fmaf(xv.w, wB1[3], a1[r]);
                a2[r] = fmaf(xv.x, wB2[0], a2[r]); a2[r] = fmaf(xv.y, wB2[1], a2[r]);
                a2[r] = fmaf(xv.z, wB2[2], a2[r]); a2[r] = fmaf(xv.w, wB2[3], a2[r]);
                a3[r] = fmaf(xv.x, wB3[0], a3[r]); a3[r] = fmaf(xv.y, wB3[1], a3[r]);
                a3[r] = fmaf(xv.z, wB3[2], a3[r]); a3[r] = fmaf(xv.w, wB3[3], a3[r]);
            }
        }

#pragma unroll
        for (int r = 0; r < 16; ++r) {
            const float v0 = m1a[r] + ((a0[r] + bg0) - m1a[r]) * 0.5f;
            const bool s0 = (v0 - 1.0f) > 0.0f;
            m1a[r] = s0 ? 0.0f : v0;
            const unsigned long long k0 = __ballot(s0);
            const float v1 = m1b[r] + ((a1[r] + bg1) - m1b[r]) * 0.5f;
            const bool s1 = (v1 - 1.0f) > 0.0f;
            m1b[r] = s1 ? 0.0f : v1;
            const unsigned long long k1 = __ballot(s1);
            if (lane == 0) {
                bits1[r][wave] = k0; bits1[r][4 + wave] = k1;
                if (k0 | k1) atomicOr(&rowflag[0], 1u << r);
            }
        }
        __syncthreads();

        if (tid == 0) rowflag[2] = 0;
        if (t + 1 < TT) {
            const float* src = x + (((size_t)(t + 1) * B) + row0) * DD;
#pragma unroll
            for (int u = 0; u < 8; ++u)
                GLD_LDS(src + ((u * 256 + tid) << 2), xs + ((u * 256 + wave * 64) << 2));
        }

        {
            const unsigned int rf = rowflag[0];
#pragma unroll 1
            for (int r = 0; r < 16; ++r) {
                float p0 = bp0, p1 = bp1;
                if (rf & (1u << r)) {
#pragma unroll 1
                    for (int w = 0; w < 8; ++w) {
                        unsigned long long m = bits1[r][w];
                        while (m) {
                            const int b = __builtin_ctzll(m); m &= (m - 1);
                            const float* wp = Wpc + (size_t)((w << 6) + b) * HIDN + tid;
                            p0 += wp[0]; p1 += wp[256];
                        }
                    }
                }
                const float v0 = m2a[r] + (p0 - m2a[r]) * 0.5f;
                const bool s0 = (v0 - 1.0f) > 0.0f;
                m2a[r] = s0 ? 0.0f : v0;
                const unsigned long long k0 = __ballot(s0);
                const float v1 = m2b[r] + (p1 - m2b[r]) * 0.5f;
                const bool s1 = (v1 - 1.0f) > 0.0f;
                m2b[r] = s1 ? 0.0f : v1;
                const unsigned long long k1 = __ballot(s1);
                if (lane == 0) {
                    bits2[r][wave] = k0; bits2[r][4 + wave] = k1;
                    if (k0 | k1) atomicOr(&rowflag[1], 1u << r);
                }
            }
        }
        __syncthreads();

        if (tid == 0) rowflag[0] = 0;

        {
            const unsigned int rf = rowflag[1];
#pragma unroll 1
            for (int r = 0; r < 16; ++r) {
                float p0 = a2[r] + bd0, p1 = a3[r] + bd1;
                if (rf & (1u << r)) {
#pragma unroll 1
                    for (int w = 0; w < 8; ++w) {
                        unsigned long long m = bits2[r][w];
                        while (m) {
                            const int b = __builtin_ctzll(m); m &= (m - 1);
                            const float* wp = Wd1 + (size_t)(DD + (w << 6) + b) * HIDN + tid;
                            p0 += wp[0]; p1 += wp[256];
                        }
                    }
                }
                const float v0 = m3a[r] + (p0 - m3a[r]) * 0.5f;
                const bool s0 = (v0 - 1.0f) > 0.0f;
                m3a[r] = s0 ? 0.0f : v0;
                const unsigned long long k0 = __ballot(s0);
                const float v1 = m3b[r] + (p1 - m3b[r]) * 0.5f;
                const bool s1 = (v1 - 1.0f) > 0.0f;
                m3b[r] = s1 ? 0.0f : v1;
                const unsigned long long k1 = __ballot(s1);
                if (lane == 0) {
                    bits3[r][wave] = k0; bits3[r][4 + wave] = k1;
                    if (k0 | k1) atomicOr(&rowflag[2], 1u << r);
                }
            }
        }
        __syncthreads();

        if (tid == 0) rowflag[1] = 0;

        {
            const unsigned int rf = rowflag[2];
            if (owrite && (rf & (1u << orow))) {
#pragma unroll 1
                for (int w = 0; w < 8; ++w) {
                    unsigned long long m = bits3[orow][w];
                    while (m) {
                        const int b = __builtin_ctzll(m); m &= (m - 1);
                        out_acc += Wd2[(size_t)((w << 6) + b) * OUTN + ocol];
                    }
                }
            }
        }
    }

    if (owrite) out[(row0 + orow) * OUTN + ocol] = out_acc * 0.0625f + bd2[ocol];
}

// Workspace: Whi 1MiB | Wlo 1MiB | Xh 256MiB | Xl 256MiB | G 1GiB  (<= 2GiB)
extern "C" void kernel_launch(void* const* d_in, const int* in_sizes, int n_in,
                              void* d_out, int out_size, void* d_ws, size_t ws_size,
                              hipStream_t stream) {
    const float* x   = (const float*)d_in[0];
    const float* Wgc = (const float*)d_in[1];
    const float* bgc = (const float*)d_in[2];
    const float* Wpc = (const float*)d_in[3];
    const float* bpc = (const float*)d_in[4];
    const float* Wd1 = (const float*)d_in[5];
    const float* bd1 = (const float*)d_in[6];
    const float* Wd2 = (const float*)d_in[7];
    const float* bd2 = (const float*)d_in[8];
    const int B = in_sizes[0] / (TT * DD);

    const size_t MB = (size_t)1 << 20;
    const size_t xp_bytes = (size_t)TT * B * DD * 2;        // each of Xh, Xl
    const size_t g_bytes  = (size_t)TT * B * NTOT * 4;
    const size_t need = 2 * MB + 2 * xp_bytes + g_bytes;
    const int nrt = (TT * B) / 128;                         // 128-row tiles

    const bool ok = d_ws != nullptr && ws_size >= need &&
                    (B % 128) == 0 && (nrt % 8) == 0 && (B % R2) == 0;

    if (!ok) {
        hipLaunchKernelGGL(snn_fused_fb, dim3(B / 16), dim3(256), 0, stream,
                           x, Wgc, bgc, Wpc, bpc, Wd1, bd1, Wd2, bd2,
                           (float*)d_out, B);
        return;
    }

    _Float16* Whi = reinterpret_cast<_Float16*>(d_ws);
    _Float16* Wlo = Whi + (size_t)64 * 16 * 64 * 8;                 // +1 MiB
    _Float16* Xh  = reinterpret_cast<_Float16*>((char*)d_ws + 2 * MB);
    _Float16* Xl  = Xh + (size_t)TT * B * DD;
    float*    G   = reinterpret_cast<float*>((char*)d_ws + 2 * MB + 2 * xp_bytes);

    hipLaunchKernelGGL(pack_w, dim3(256), dim3(256), 0, stream, Wgc, Wd1, Whi, Wlo);
    hipLaunchKernelGGL(pack_x, dim3((TT * B) / 16), dim3(256), 0, stream, x, Xh, Xl);
    hipLaunchKernelGGL(gemm_pre, dim3(nrt * 8), dim3(256), 0, stream,
                       Xh, Xl, Whi, Wlo, G, nrt);
    hipLaunchKernelGGL(snn_recur, dim3(B / R2), dim3(256), 0, stream,
                       G, bgc, Wpc, bpc, Wd1, bd1, Wd2, bd2,
                       (float*)d_out, B);
}